// Round 1
// baseline (439.912 us; speedup 1.0000x reference)
//
#include <hip/hip_runtime.h>
#include <math.h>

#define B   4
#define V   360
#define D   512
#define ENC 64
#define CH  9
#define P2  4096
#define NCHUNK 24
#define VCHUNK 15   // 360 / 24

// ---------------------------------------------------------------------------
// Kernel 1: 3x3 conv (pad 1), NCHW in, channel-last padded out [B,V,D,SS]
// ---------------------------------------------------------------------------
__global__ __launch_bounds__(256) void conv_kernel(
    const float* __restrict__ feat,   // [B,ENC,V,D]
    const float* __restrict__ w,      // [CH,ENC,3,3]
    const float* __restrict__ bias,   // [CH]
    float* __restrict__ sino,         // [B,V,D,SS]
    int ss)
{
    __shared__ float lw[CH * ENC * 9];
    const int tid = threadIdx.x;
    for (int i = tid; i < CH * ENC * 9; i += 256) lw[i] = w[i];
    __syncthreads();

    const int bx = blockIdx.x;
    const int v  = bx >> 1;                 // 0..359
    const int d  = ((bx & 1) << 8) + tid;   // 0..511
    const int b  = blockIdx.y;

    float acc[CH];
    #pragma unroll
    for (int oc = 0; oc < CH; ++oc) acc[oc] = bias[oc];

    const float* fb = feat + (size_t)b * ENC * V * D;
    const bool vm = v > 0, vp = v < V - 1, dm = d > 0, dp = d < D - 1;

    for (int ic = 0; ic < ENC; ++ic) {
        const float* f = fb + (size_t)ic * V * D + (size_t)v * D + d;
        float t[9];
        t[0] = (vm && dm) ? f[-D - 1] : 0.f;
        t[1] =  vm        ? f[-D]     : 0.f;
        t[2] = (vm && dp) ? f[-D + 1] : 0.f;
        t[3] =  dm        ? f[-1]     : 0.f;
        t[4] =              f[0];
        t[5] =  dp        ? f[1]      : 0.f;
        t[6] = (vp && dm) ? f[D - 1]  : 0.f;
        t[7] =  vp        ? f[D]      : 0.f;
        t[8] = (vp && dp) ? f[D + 1]  : 0.f;
        const float* lwp = lw + ic * 9;
        #pragma unroll
        for (int oc = 0; oc < CH; ++oc) {
            const float* ww = lwp + oc * (ENC * 9);
            #pragma unroll
            for (int k = 0; k < 9; ++k) acc[oc] = fmaf(t[k], ww[k], acc[oc]);
        }
    }

    float* so = sino + (size_t)((b * V + v) * D + d) * ss;
    #pragma unroll
    for (int oc = 0; oc < CH; ++oc) so[oc] = acc[oc];
}

// ---------------------------------------------------------------------------
// Kernel 2: grid-sample (nearest, 2 shifts) + Fourier decode + bilinear BP,
// partial reduction over a V-chunk.
// ---------------------------------------------------------------------------
template <int SS>
__global__ __launch_bounds__(256) void sample_kernel(
    const float* __restrict__ sino,      // [B,V,D,SS]
    const float* __restrict__ sinogram,  // [B,1,V,D]
    const float* __restrict__ grid,      // [B,V,P2,2]
    const float* __restrict__ sq,        // [B,1,V,P2]
    float* __restrict__ partial)         // [NCHUNK,B,P2]
{
    const int p  = blockIdx.x * 256 + threadIdx.x;
    const int v0 = blockIdx.y * VCHUNK;
    const int b  = blockIdx.z;

    const float* sg = sinogram + (size_t)b * V * D;
    const float* sb = sino + (size_t)b * V * D * SS;

    float acc = 0.f;
    for (int v = v0; v < v0 + VCHUNK; ++v) {
        const size_t gi = (size_t)(b * V + v) * P2 + p;
        const float gx = grid[gi * 2 + 0];
        const float gy = grid[gi * 2 + 1];
        const float s  = sq[gi];

        // nearest y (same for both shifts)
        float fy = ((gy + 1e-6f + 1.f) * (float)V - 1.f) * 0.5f;
        int   yi = (int)fminf(fmaxf(rintf(fy), 0.f), (float)(V - 1));

        float val[2], len[2];
        #pragma unroll
        for (int sft = 0; sft < 2; ++sft) {
            const float sxv = (sft == 0) ? (-1.f / (float)D) : (1.f / (float)D);
            float fx = ((gx + sxv + 1e-6f + 1.f) * (float)D - 1.f) * 0.5f;
            int   xi = (int)fminf(fmaxf(rintf(fx), 0.f), (float)(D - 1));
            float qc = ((float)xi + 0.5f) * (2.f / (float)D) - 1.f;
            float rel = (gx - qc) * (float)D;

            float q[9];
            const float* qp = sb + (size_t)(yi * D + xi) * SS;
            if (SS == 16) {
                const float4* q4 = (const float4*)qp;
                float4 a = q4[0], c = q4[1];
                q[0] = a.x; q[1] = a.y; q[2] = a.z; q[3] = a.w;
                q[4] = c.x; q[5] = c.y; q[6] = c.z; q[7] = c.w;
                q[8] = qp[8];
            } else {
                #pragma unroll
                for (int k = 0; k < 9; ++k) q[k] = qp[k];
            }

            const float ang = rel * 1.5707963267948966f;  // OMEGA
            float s1, c1;
            __sincosf(ang, &s1, &c1);
            const float c2 = fmaf(2.f * c1, c1, -1.f);
            const float s2 = 2.f * c1 * s1;
            const float c3 = fmaf(2.f * c1, c2, -c1);
            const float s3 = fmaf(2.f * c1, s2, -s1);
            const float c4 = fmaf(2.f * c1, c3, -c2);
            const float s4 = fmaf(2.f * c1, s3, -s2);

            float vv = q[0];
            vv = fmaf(q[1], c1, vv); vv = fmaf(q[2], c2, vv);
            vv = fmaf(q[3], c3, vv); vv = fmaf(q[4], c4, vv);
            vv = fmaf(q[5], s1, vv); vv = fmaf(q[6], s2, vv);
            vv = fmaf(q[7], s3, vv); vv = fmaf(q[8], s4, vv);
            val[sft] = vv;
            len[sft] = fabsf(rel) + 1e-4f;
        }
        const float tot   = len[0] + len[1];
        const float recon = (val[0] * len[1] + val[1] * len[0]) / tot;

        // bilinear back-projection of raw sinogram (original grid, no eps)
        float fxb = fminf(fmaxf(((gx + 1.f) * (float)D - 1.f) * 0.5f, 0.f), (float)(D - 1));
        float fyb = fminf(fmaxf(((gy + 1.f) * (float)V - 1.f) * 0.5f, 0.f), (float)(V - 1));
        float x0 = floorf(fxb), y0 = floorf(fyb);
        float wx = fxb - x0,    wy = fyb - y0;
        int x0i = (int)x0, y0i = (int)y0;
        int x1i = min(x0i + 1, D - 1), y1i = min(y0i + 1, V - 1);
        float v00 = sg[y0i * D + x0i], v01 = sg[y0i * D + x1i];
        float v10 = sg[y1i * D + x0i], v11 = sg[y1i * D + x1i];
        float bp = v00 * (1.f - wx) * (1.f - wy) + v01 * wx * (1.f - wy)
                 + v10 * (1.f - wx) * wy        + v11 * wx * wy;

        acc += (recon + bp) * s * 1e4f;
    }
    partial[((size_t)blockIdx.y * B + b) * P2 + p] = acc;
}

// ---------------------------------------------------------------------------
// Kernel 3: fold the NCHUNK partials
// ---------------------------------------------------------------------------
__global__ __launch_bounds__(256) void reduce_kernel(
    const float* __restrict__ partial, float* __restrict__ out)
{
    const int i = blockIdx.x * 256 + threadIdx.x;   // 0..B*P2-1
    float a = 0.f;
    #pragma unroll
    for (int c = 0; c < NCHUNK; ++c) a += partial[(size_t)c * B * P2 + i];
    out[i] = a;
}

// ---------------------------------------------------------------------------
extern "C" void kernel_launch(void* const* d_in, const int* in_sizes, int n_in,
                              void* d_out, int out_size, void* d_ws, size_t ws_size,
                              hipStream_t stream)
{
    const float* sinogram = (const float*)d_in[0];
    const float* feat     = (const float*)d_in[1];
    const float* grid     = (const float*)d_in[2];
    const float* sq       = (const float*)d_in[3];
    const float* w        = (const float*)d_in[4];
    const float* bias     = (const float*)d_in[5];
    float* out = (float*)d_out;

    const size_t part_bytes = (size_t)NCHUNK * B * P2 * sizeof(float);
    const size_t need16 = (size_t)B * V * D * 16 * sizeof(float) + part_bytes;
    const int ss = (ws_size >= need16) ? 16 : 9;

    float* sino    = (float*)d_ws;
    float* partial = (float*)((char*)d_ws + (size_t)B * V * D * ss * sizeof(float));

    conv_kernel<<<dim3(V * 2, B), 256, 0, stream>>>(feat, w, bias, sino, ss);

    dim3 sgrid(P2 / 256, NCHUNK, B);
    if (ss == 16)
        sample_kernel<16><<<sgrid, 256, 0, stream>>>(sino, sinogram, grid, sq, partial);
    else
        sample_kernel<9><<<sgrid, 256, 0, stream>>>(sino, sinogram, grid, sq, partial);

    reduce_kernel<<<dim3((B * P2) / 256), 256, 0, stream>>>(partial, out);
}

// Round 2
// 314.485 us; speedup vs baseline: 1.3988x; 1.3988x over previous
//
#include <hip/hip_runtime.h>
#include <math.h>

#define B   4
#define V   360
#define D   512
#define ENC 64
#define CH  9
#define P2  4096
#define NCHUNK 24
#define VCHUNK 15   // 360 / 24
#define DPT 4       // pixels per thread along d (conv)

// ---------------------------------------------------------------------------
// Kernel 1: 3x3 conv (pad 1), NCHW in, channel-last padded out [B,V,D,SS]
// Register-blocked: 4 pixels/thread, weights via wave-uniform (SGPR) loads.
// Block = 256 threads = 2 output rows x 512 d. Grid = 720 blocks (XCD-swizzled).
// ---------------------------------------------------------------------------
template <int SS>
__global__ __launch_bounds__(256) void conv_kernel(
    const float* __restrict__ feat,   // [B,ENC,V,D]
    const float* __restrict__ w,      // [CH,ENC,3,3]
    const float* __restrict__ bias,   // [CH]
    float* __restrict__ sino)         // [B,V,D,SS]
{
    // 720 blocks linear; XCD-chunk swizzle (720 % 8 == 0 -> bijective)
    const int bid = blockIdx.x;
    const int sw  = (bid & 7) * 90 + (bid >> 3);
    const int b   = sw / 180;
    const int vt  = sw % 180;
    const int tr  = threadIdx.x >> 7;          // row within tile: 0..1
    const int v   = vt * 2 + tr;
    const int d0  = (threadIdx.x & 127) * DPT; // 0..508

    float acc[CH][DPT];
    #pragma unroll
    for (int oc = 0; oc < CH; ++oc) {
        const float bv = bias[oc];
        #pragma unroll
        for (int p = 0; p < DPT; ++p) acc[oc][p] = bv;
    }

    const float* fb = feat + ((size_t)b * ENC * V + v) * D + d0;
    const bool vm = v > 0, vp = v < V - 1;
    const bool dm = d0 > 0, dp = (d0 + DPT) < D;

    for (int ic = 0; ic < ENC; ++ic) {
        const float* f = fb + (size_t)ic * (V * D);
        float r[3][DPT + 2];
        #pragma unroll
        for (int rr = 0; rr < 3; ++rr) {
            const float* fr = f + (rr - 1) * D;
            const bool ok = (rr == 0) ? vm : ((rr == 2) ? vp : true);
            float4 c = ok ? *(const float4*)fr : float4{0.f, 0.f, 0.f, 0.f};
            r[rr][1] = c.x; r[rr][2] = c.y; r[rr][3] = c.z; r[rr][4] = c.w;
            r[rr][0] = (ok && dm) ? fr[-1]  : 0.f;
            r[rr][5] = (ok && dp) ? fr[DPT] : 0.f;
        }
        #pragma unroll
        for (int oc = 0; oc < CH; ++oc) {
            // wave-uniform address -> scalar (SGPR) loads
            const float* ww = w + ((size_t)oc * ENC + ic) * 9;
            #pragma unroll
            for (int kr = 0; kr < 3; ++kr) {
                #pragma unroll
                for (int kc = 0; kc < 3; ++kc) {
                    const float wv = ww[kr * 3 + kc];
                    #pragma unroll
                    for (int p = 0; p < DPT; ++p)
                        acc[oc][p] = fmaf(r[kr][p + kc], wv, acc[oc][p]);
                }
            }
        }
    }

    #pragma unroll
    for (int p = 0; p < DPT; ++p) {
        float* so = sino + (size_t)(((size_t)b * V + v) * D + d0 + p) * SS;
        if (SS == 16) {
            float4* so4 = (float4*)so;
            so4[0] = float4{acc[0][p], acc[1][p], acc[2][p], acc[3][p]};
            so4[1] = float4{acc[4][p], acc[5][p], acc[6][p], acc[7][p]};
            so[8]  = acc[8][p];
        } else {
            #pragma unroll
            for (int oc = 0; oc < CH; ++oc) so[oc] = acc[oc][p];
        }
    }
}

// ---------------------------------------------------------------------------
// Kernel 2: grid-sample (nearest, 2 shifts) + Fourier decode + bilinear BP,
// partial reduction over a V-chunk.
// ---------------------------------------------------------------------------
template <int SS>
__global__ __launch_bounds__(256) void sample_kernel(
    const float* __restrict__ sino,      // [B,V,D,SS]
    const float* __restrict__ sinogram,  // [B,1,V,D]
    const float* __restrict__ grid,      // [B,V,P2,2]
    const float* __restrict__ sq,        // [B,1,V,P2]
    float* __restrict__ partial)         // [NCHUNK,B,P2]
{
    const int p  = blockIdx.x * 256 + threadIdx.x;
    const int v0 = blockIdx.y * VCHUNK;
    const int b  = blockIdx.z;

    const float* sg = sinogram + (size_t)b * V * D;
    const float* sb = sino + (size_t)b * V * D * SS;

    float acc = 0.f;
    for (int v = v0; v < v0 + VCHUNK; ++v) {
        const size_t gi = (size_t)(b * V + v) * P2 + p;
        const float gx = grid[gi * 2 + 0];
        const float gy = grid[gi * 2 + 1];
        const float s  = sq[gi];

        // nearest y (same for both shifts)
        float fy = ((gy + 1e-6f + 1.f) * (float)V - 1.f) * 0.5f;
        int   yi = (int)fminf(fmaxf(rintf(fy), 0.f), (float)(V - 1));

        float val[2], len[2];
        #pragma unroll
        for (int sft = 0; sft < 2; ++sft) {
            const float sxv = (sft == 0) ? (-1.f / (float)D) : (1.f / (float)D);
            float fx = ((gx + sxv + 1e-6f + 1.f) * (float)D - 1.f) * 0.5f;
            int   xi = (int)fminf(fmaxf(rintf(fx), 0.f), (float)(D - 1));
            float qc = ((float)xi + 0.5f) * (2.f / (float)D) - 1.f;
            float rel = (gx - qc) * (float)D;

            float q[9];
            const float* qp = sb + (size_t)(yi * D + xi) * SS;
            if (SS == 16) {
                const float4* q4 = (const float4*)qp;
                float4 a = q4[0], c = q4[1];
                q[0] = a.x; q[1] = a.y; q[2] = a.z; q[3] = a.w;
                q[4] = c.x; q[5] = c.y; q[6] = c.z; q[7] = c.w;
                q[8] = qp[8];
            } else {
                #pragma unroll
                for (int k = 0; k < 9; ++k) q[k] = qp[k];
            }

            const float ang = rel * 1.5707963267948966f;  // OMEGA
            float s1, c1;
            __sincosf(ang, &s1, &c1);
            const float c2 = fmaf(2.f * c1, c1, -1.f);
            const float s2 = 2.f * c1 * s1;
            const float c3 = fmaf(2.f * c1, c2, -c1);
            const float s3 = fmaf(2.f * c1, s2, -s1);
            const float c4 = fmaf(2.f * c1, c3, -c2);
            const float s4 = fmaf(2.f * c1, s3, -s2);

            float vv = q[0];
            vv = fmaf(q[1], c1, vv); vv = fmaf(q[2], c2, vv);
            vv = fmaf(q[3], c3, vv); vv = fmaf(q[4], c4, vv);
            vv = fmaf(q[5], s1, vv); vv = fmaf(q[6], s2, vv);
            vv = fmaf(q[7], s3, vv); vv = fmaf(q[8], s4, vv);
            val[sft] = vv;
            len[sft] = fabsf(rel) + 1e-4f;
        }
        const float tot   = len[0] + len[1];
        const float recon = (val[0] * len[1] + val[1] * len[0]) / tot;

        // bilinear back-projection of raw sinogram (original grid, no eps)
        float fxb = fminf(fmaxf(((gx + 1.f) * (float)D - 1.f) * 0.5f, 0.f), (float)(D - 1));
        float fyb = fminf(fmaxf(((gy + 1.f) * (float)V - 1.f) * 0.5f, 0.f), (float)(V - 1));
        float x0 = floorf(fxb), y0 = floorf(fyb);
        float wx = fxb - x0,    wy = fyb - y0;
        int x0i = (int)x0, y0i = (int)y0;
        int x1i = min(x0i + 1, D - 1), y1i = min(y0i + 1, V - 1);
        float v00 = sg[y0i * D + x0i], v01 = sg[y0i * D + x1i];
        float v10 = sg[y1i * D + x0i], v11 = sg[y1i * D + x1i];
        float bp = v00 * (1.f - wx) * (1.f - wy) + v01 * wx * (1.f - wy)
                 + v10 * (1.f - wx) * wy        + v11 * wx * wy;

        acc += (recon + bp) * s * 1e4f;
    }
    partial[((size_t)blockIdx.y * B + b) * P2 + p] = acc;
}

// ---------------------------------------------------------------------------
// Kernel 3: fold the NCHUNK partials
// ---------------------------------------------------------------------------
__global__ __launch_bounds__(256) void reduce_kernel(
    const float* __restrict__ partial, float* __restrict__ out)
{
    const int i = blockIdx.x * 256 + threadIdx.x;   // 0..B*P2-1
    float a = 0.f;
    #pragma unroll
    for (int c = 0; c < NCHUNK; ++c) a += partial[(size_t)c * B * P2 + i];
    out[i] = a;
}

// ---------------------------------------------------------------------------
extern "C" void kernel_launch(void* const* d_in, const int* in_sizes, int n_in,
                              void* d_out, int out_size, void* d_ws, size_t ws_size,
                              hipStream_t stream)
{
    const float* sinogram = (const float*)d_in[0];
    const float* feat     = (const float*)d_in[1];
    const float* grid     = (const float*)d_in[2];
    const float* sq       = (const float*)d_in[3];
    const float* w        = (const float*)d_in[4];
    const float* bias     = (const float*)d_in[5];
    float* out = (float*)d_out;

    const size_t part_bytes = (size_t)NCHUNK * B * P2 * sizeof(float);
    const size_t need16 = (size_t)B * V * D * 16 * sizeof(float) + part_bytes;
    const int ss = (ws_size >= need16) ? 16 : 9;

    float* sino    = (float*)d_ws;
    float* partial = (float*)((char*)d_ws + (size_t)B * V * D * ss * sizeof(float));

    dim3 sgrid(P2 / 256, NCHUNK, B);
    if (ss == 16) {
        conv_kernel<16><<<dim3(720), 256, 0, stream>>>(feat, w, bias, sino);
        sample_kernel<16><<<sgrid, 256, 0, stream>>>(sino, sinogram, grid, sq, partial);
    } else {
        conv_kernel<9><<<dim3(720), 256, 0, stream>>>(feat, w, bias, sino);
        sample_kernel<9><<<sgrid, 256, 0, stream>>>(sino, sinogram, grid, sq, partial);
    }

    reduce_kernel<<<dim3((B * P2) / 256), 256, 0, stream>>>(partial, out);
}

// Round 3
// 297.428 us; speedup vs baseline: 1.4791x; 1.0573x over previous
//
#include <hip/hip_runtime.h>
#include <hip/hip_fp16.h>
#include <math.h>

#define B   4
#define V   360
#define D   512
#define ENC 64
#define CH  9
#define P2  4096
#define NCHUNK 45
#define VCHUNK 8    // 360 / 45
#define DPT 8       // pixels per thread along d (conv)
#define RECH 16     // halfs per record (32 B)

// ---------------------------------------------------------------------------
// Kernel 1: 3x3 conv (pad 1), NCHW in, fp16 channel-packed records [B,V,D,16h]
// 8 pixels/thread, weights via wave-uniform (SGPR) loads.
// Block = 256 threads = 4 output rows x 512 d. Grid = 360 blocks.
// XCD swizzle puts batch b on XCDs {2b,2b+1} (matches sample kernel).
// ---------------------------------------------------------------------------
__global__ __launch_bounds__(256) void conv_kernel(
    const float* __restrict__ feat,   // [B,ENC,V,D]
    const float* __restrict__ w,      // [CH,ENC,3,3]
    const float* __restrict__ bias,   // [CH]
    __half* __restrict__ sino)        // [B,V,D,RECH]
{
    const int bid = blockIdx.x;                // 360 = 8 * 45, bijective swizzle
    const int sw  = (bid & 7) * 45 + (bid >> 3);
    const int b   = sw / 90;
    const int vt  = sw % 90;
    const int tr  = threadIdx.x >> 6;          // row within tile: 0..3
    const int v   = vt * 4 + tr;
    const int d0  = (threadIdx.x & 63) * DPT;  // 0..504

    float acc[CH][DPT];
    #pragma unroll
    for (int oc = 0; oc < CH; ++oc) {
        const float bv = bias[oc];
        #pragma unroll
        for (int p = 0; p < DPT; ++p) acc[oc][p] = bv;
    }

    const float* fb = feat + ((size_t)b * ENC * V + v) * D + d0;
    const bool vm = v > 0, vp = v < V - 1;
    const bool dm = d0 > 0, dp = (d0 + DPT) < D;

    for (int ic = 0; ic < ENC; ++ic) {
        const float* f = fb + (size_t)ic * (V * D);
        float r[3][DPT + 2];
        #pragma unroll
        for (int rr = 0; rr < 3; ++rr) {
            const float* fr = f + (rr - 1) * D;
            const bool ok = (rr == 0) ? vm : ((rr == 2) ? vp : true);
            float4 c0 = ok ? *(const float4*)fr       : float4{0.f, 0.f, 0.f, 0.f};
            float4 c1 = ok ? *(const float4*)(fr + 4) : float4{0.f, 0.f, 0.f, 0.f};
            r[rr][1] = c0.x; r[rr][2] = c0.y; r[rr][3] = c0.z; r[rr][4] = c0.w;
            r[rr][5] = c1.x; r[rr][6] = c1.y; r[rr][7] = c1.z; r[rr][8] = c1.w;
            r[rr][0]       = (ok && dm) ? fr[-1]   : 0.f;
            r[rr][DPT + 1] = (ok && dp) ? fr[DPT]  : 0.f;
        }
        #pragma unroll
        for (int oc = 0; oc < CH; ++oc) {
            // wave-uniform address -> scalar (SGPR) loads
            const float* ww = w + ((size_t)oc * ENC + ic) * 9;
            #pragma unroll
            for (int kr = 0; kr < 3; ++kr) {
                #pragma unroll
                for (int kc = 0; kc < 3; ++kc) {
                    const float wv = ww[kr * 3 + kc];
                    #pragma unroll
                    for (int p = 0; p < DPT; ++p)
                        acc[oc][p] = fmaf(r[kr][p + kc], wv, acc[oc][p]);
                }
            }
        }
    }

    #pragma unroll
    for (int p = 0; p < DPT; ++p) {
        __half* rec = sino + (size_t)(((size_t)b * V + v) * D + d0 + p) * RECH;
        union { __half2 h; unsigned u; } cv;
        uint4 pk;
        cv.h = __floats2half2_rn(acc[0][p], acc[1][p]); pk.x = cv.u;
        cv.h = __floats2half2_rn(acc[2][p], acc[3][p]); pk.y = cv.u;
        cv.h = __floats2half2_rn(acc[4][p], acc[5][p]); pk.z = cv.u;
        cv.h = __floats2half2_rn(acc[6][p], acc[7][p]); pk.w = cv.u;
        *(uint4*)rec = pk;
        cv.h = __floats2half2_rn(acc[8][p], 0.f);
        *(unsigned*)(rec + 8) = cv.u;
    }
}

// ---------------------------------------------------------------------------
// Kernel 2: grid-sample (nearest, 2 shifts) + Fourier decode + bilinear BP
// ---------------------------------------------------------------------------
__device__ __forceinline__ void unpack9(const __half* rec, float* q)
{
    const uint4 a = *(const uint4*)rec;
    union { unsigned u; __half2 h; } c;
    float2 f;
    c.u = a.x; f = __half22float2(c.h); q[0] = f.x; q[1] = f.y;
    c.u = a.y; f = __half22float2(c.h); q[2] = f.x; q[3] = f.y;
    c.u = a.z; f = __half22float2(c.h); q[4] = f.x; q[5] = f.y;
    c.u = a.w; f = __half22float2(c.h); q[6] = f.x; q[7] = f.y;
    const unsigned e = *(const unsigned*)(rec + 8);
    union { unsigned short us; __half hh; } c2;
    c2.us = (unsigned short)e;
    q[8] = __half2float(c2.hh);
}

__device__ __forceinline__ float point_contrib(
    int b, int v, int p,
    const __half* __restrict__ sb, const float* __restrict__ sg,
    const float* __restrict__ grid, const float* __restrict__ sq)
{
    const size_t gi = (size_t)(b * V + v) * P2 + p;
    const double gd = __builtin_nontemporal_load((const double*)grid + gi);
    const unsigned long long gu = __double_as_longlong(gd);
    const float gx = __uint_as_float((unsigned)gu);
    const float gy = __uint_as_float((unsigned)(gu >> 32));
    const float s  = __builtin_nontemporal_load(sq + gi);

    // nearest y (same for both shifts)
    const float fy = ((gy + 1e-6f + 1.f) * (float)V - 1.f) * 0.5f;
    const int   yi = (int)fminf(fmaxf(rintf(fy), 0.f), (float)(V - 1));
    const float fx0 = ((gx + 1e-6f + 1.f) * (float)D - 1.f) * 0.5f;

    float val[2], len[2];
    #pragma unroll
    for (int sft = 0; sft < 2; ++sft) {
        const float fx = (sft == 0) ? (fx0 - 0.5f) : (fx0 + 0.5f);
        const int   xi = (int)fminf(fmaxf(rintf(fx), 0.f), (float)(D - 1));
        const float qc = ((float)xi + 0.5f) * (2.f / (float)D) - 1.f;
        const float rel = (gx - qc) * (float)D;

        float q[9];
        unpack9(sb + (size_t)(yi * D + xi) * RECH, q);

        const float ang = rel * 1.5707963267948966f;  // OMEGA
        float s1, c1;
        __sincosf(ang, &s1, &c1);
        const float c2 = fmaf(2.f * c1, c1, -1.f);
        const float s2 = 2.f * c1 * s1;
        const float c3 = fmaf(2.f * c1, c2, -c1);
        const float s3 = fmaf(2.f * c1, s2, -s1);
        const float c4 = fmaf(2.f * c1, c3, -c2);
        const float s4 = fmaf(2.f * c1, s3, -s2);

        float vv = q[0];
        vv = fmaf(q[1], c1, vv); vv = fmaf(q[2], c2, vv);
        vv = fmaf(q[3], c3, vv); vv = fmaf(q[4], c4, vv);
        vv = fmaf(q[5], s1, vv); vv = fmaf(q[6], s2, vv);
        vv = fmaf(q[7], s3, vv); vv = fmaf(q[8], s4, vv);
        val[sft] = vv;
        len[sft] = fabsf(rel) + 1e-4f;
    }
    const float tot   = len[0] + len[1];
    const float recon = (val[0] * len[1] + val[1] * len[0]) / tot;

    // bilinear back-projection of raw sinogram (original grid, no eps)
    float fxb = fminf(fmaxf(((gx + 1.f) * (float)D - 1.f) * 0.5f, 0.f), (float)(D - 1));
    float fyb = fminf(fmaxf(((gy + 1.f) * (float)V - 1.f) * 0.5f, 0.f), (float)(V - 1));
    const float x0 = floorf(fxb), y0 = floorf(fyb);
    const float wx = fxb - x0,    wy = fyb - y0;
    const int x0i = (int)x0, y0i = (int)y0;
    const int x1i = min(x0i + 1, D - 1), y1i = min(y0i + 1, V - 1);
    const float v00 = sg[y0i * D + x0i], v01 = sg[y0i * D + x1i];
    const float v10 = sg[y1i * D + x0i], v11 = sg[y1i * D + x1i];
    const float bp = v00 * (1.f - wx) * (1.f - wy) + v01 * wx * (1.f - wy)
                   + v10 * (1.f - wx) * wy        + v11 * wx * wy;

    return (recon + bp) * s * 1e4f;
}

__global__ __launch_bounds__(256) void sample_kernel(
    const __half* __restrict__ sino,     // [B,V,D,RECH]
    const float* __restrict__ sinogram,  // [B,1,V,D]
    const float* __restrict__ grid,      // [B,V,P2,2]
    const float* __restrict__ sq,        // [B,1,V,P2]
    float* __restrict__ partial)         // [NCHUNK,B,P2]
{
    // 2880 blocks = 8 XCDs * 360. Batch b owned by XCDs {2b, 2b+1} so each
    // XCD's L2 only caches its batch's 5.9 MB gather table.
    const int bid = blockIdx.x;
    const int xcd = bid & 7;
    const int b   = xcd >> 1;
    const int idx = ((bid >> 3) << 1) | (xcd & 1);  // 0..719
    const int chunk = idx >> 4;                     // 0..44
    const int p  = (idx & 15) * 256 + threadIdx.x;
    const int v0 = chunk * VCHUNK;

    const float* sg = sinogram + (size_t)b * V * D;
    const __half* sb = sino + (size_t)b * V * D * RECH;

    float acc = 0.f;
    #pragma unroll 1
    for (int v = v0; v < v0 + VCHUNK; v += 2) {
        const float c0 = point_contrib(b, v,     p, sb, sg, grid, sq);
        const float c1 = point_contrib(b, v + 1, p, sb, sg, grid, sq);
        acc += c0;
        acc += c1;
    }
    __builtin_nontemporal_store(acc, partial + ((size_t)chunk * B + b) * P2 + p);
}

// ---------------------------------------------------------------------------
// Kernel 3: fold the NCHUNK partials
// ---------------------------------------------------------------------------
__global__ __launch_bounds__(256) void reduce_kernel(
    const float* __restrict__ partial, float* __restrict__ out)
{
    const int i = blockIdx.x * 256 + threadIdx.x;   // 0..B*P2-1
    float a = 0.f;
    #pragma unroll
    for (int c = 0; c < NCHUNK; ++c)
        a += __builtin_nontemporal_load(partial + (size_t)c * B * P2 + i);
    out[i] = a;
}

// ---------------------------------------------------------------------------
extern "C" void kernel_launch(void* const* d_in, const int* in_sizes, int n_in,
                              void* d_out, int out_size, void* d_ws, size_t ws_size,
                              hipStream_t stream)
{
    const float* sinogram = (const float*)d_in[0];
    const float* feat     = (const float*)d_in[1];
    const float* grid     = (const float*)d_in[2];
    const float* sq       = (const float*)d_in[3];
    const float* w        = (const float*)d_in[4];
    const float* bias     = (const float*)d_in[5];
    float* out = (float*)d_out;

    __half* sino    = (__half*)d_ws;
    float*  partial = (float*)((char*)d_ws + (size_t)B * V * D * RECH * sizeof(__half));

    conv_kernel<<<dim3(360), 256, 0, stream>>>(feat, w, bias, sino);
    sample_kernel<<<dim3(2880), 256, 0, stream>>>(sino, sinogram, grid, sq, partial);
    reduce_kernel<<<dim3((B * P2) / 256), 256, 0, stream>>>(partial, out);
}

// Round 4
// 278.312 us; speedup vs baseline: 1.5806x; 1.0687x over previous
//
#include <hip/hip_runtime.h>
#include <hip/hip_fp16.h>
#include <math.h>

#define B   4
#define V   360
#define D   512
#define ENC 64
#define CH  9
#define P2  4096
#define NCHUNK 90
#define VCHUNK 4    // 360 / 90
#define DPT 4       // pixels per thread along d (conv)
#define RECH 16     // halfs per record (32 B)

// ---------------------------------------------------------------------------
// Kernel 1: 3x3 conv (pad 1), NCHW in, fp16 channel-packed records [B,V,D,16h]
// 4 pixels/thread, weights via wave-uniform (SGPR) loads. 720 blocks,
// XCD swizzle: batch b owned by XCDs {2b,2b+1} (matches sample kernel).
// ---------------------------------------------------------------------------
__global__ __launch_bounds__(256) void conv_kernel(
    const float* __restrict__ feat,   // [B,ENC,V,D]
    const float* __restrict__ w,      // [CH,ENC,3,3]
    const float* __restrict__ bias,   // [CH]
    __half* __restrict__ sino)        // [B,V,D,RECH]
{
    const int bid = blockIdx.x;                // 720 = 8 * 90, bijective swizzle
    const int sw  = (bid & 7) * 90 + (bid >> 3);
    const int b   = sw / 180;
    const int vt  = sw % 180;
    const int tr  = threadIdx.x >> 7;          // row within tile: 0..1
    const int v   = vt * 2 + tr;
    const int d0  = (threadIdx.x & 127) * DPT; // 0..508

    float acc[CH][DPT];
    #pragma unroll
    for (int oc = 0; oc < CH; ++oc) {
        const float bv = bias[oc];
        #pragma unroll
        for (int p = 0; p < DPT; ++p) acc[oc][p] = bv;
    }

    const float* fb = feat + ((size_t)b * ENC * V + v) * D + d0;
    const bool vm = v > 0, vp = v < V - 1;
    const bool dm = d0 > 0, dp = (d0 + DPT) < D;

    for (int ic = 0; ic < ENC; ++ic) {
        const float* f = fb + (size_t)ic * (V * D);
        float r[3][DPT + 2];
        #pragma unroll
        for (int rr = 0; rr < 3; ++rr) {
            const float* fr = f + (rr - 1) * D;
            const bool ok = (rr == 0) ? vm : ((rr == 2) ? vp : true);
            float4 c = ok ? *(const float4*)fr : float4{0.f, 0.f, 0.f, 0.f};
            r[rr][1] = c.x; r[rr][2] = c.y; r[rr][3] = c.z; r[rr][4] = c.w;
            r[rr][0] = (ok && dm) ? fr[-1]  : 0.f;
            r[rr][5] = (ok && dp) ? fr[DPT] : 0.f;
        }
        #pragma unroll
        for (int oc = 0; oc < CH; ++oc) {
            // wave-uniform address -> scalar (SGPR) loads
            const float* ww = w + ((size_t)oc * ENC + ic) * 9;
            #pragma unroll
            for (int kr = 0; kr < 3; ++kr) {
                #pragma unroll
                for (int kc = 0; kc < 3; ++kc) {
                    const float wv = ww[kr * 3 + kc];
                    #pragma unroll
                    for (int p = 0; p < DPT; ++p)
                        acc[oc][p] = fmaf(r[kr][p + kc], wv, acc[oc][p]);
                }
            }
        }
    }

    #pragma unroll
    for (int p = 0; p < DPT; ++p) {
        __half* rec = sino + (size_t)(((size_t)b * V + v) * D + d0 + p) * RECH;
        union { __half2 h; unsigned u; } cv;
        uint4 pk;
        cv.h = __floats2half2_rn(acc[0][p], acc[1][p]); pk.x = cv.u;
        cv.h = __floats2half2_rn(acc[2][p], acc[3][p]); pk.y = cv.u;
        cv.h = __floats2half2_rn(acc[4][p], acc[5][p]); pk.z = cv.u;
        cv.h = __floats2half2_rn(acc[6][p], acc[7][p]); pk.w = cv.u;
        *(uint4*)rec = pk;
        cv.h = __floats2half2_rn(acc[8][p], 0.f);
        *(unsigned*)(rec + 8) = cv.u;
    }
}

// ---------------------------------------------------------------------------
// Kernel 1b: paired sinogram table  sg2[b,v,x] = (sg[x], sg[min(x+1,D-1)])
// ---------------------------------------------------------------------------
__global__ __launch_bounds__(256) void build_sg2(
    const float* __restrict__ sg, float2* __restrict__ sg2)
{
    const int i = blockIdx.x * 256 + threadIdx.x;  // B*V*D = 737280 = 2880*256
    const int x = i & (D - 1);
    const float a = sg[i];
    const float c = (x == D - 1) ? a : sg[i + 1];
    sg2[i] = float2{a, c};
}

// ---------------------------------------------------------------------------
// Kernel 2: grid-sample (nearest, 2 shifts) + Fourier decode + bilinear BP.
// 4 points per thread, phase-batched loads for MLP.
// ---------------------------------------------------------------------------
template <int PAIRED>
__global__ __launch_bounds__(256) void sample_kernel(
    const __half* __restrict__ sino,     // [B,V,D,RECH]
    const float* __restrict__ sinogram,  // [B,1,V,D]
    const float2* __restrict__ sg2,      // [B,V,D] paired
    const float* __restrict__ grid,      // [B,V,P2,2]
    const float* __restrict__ sq,        // [B,1,V,P2]
    float* __restrict__ partial)         // [NCHUNK,B,P2]
{
    // 5760 blocks = 8 XCDs * 720. Batch b owned by XCDs {2b, 2b+1}.
    const int bid = blockIdx.x;
    const int xcd = bid & 7;
    const int b   = xcd >> 1;
    const int idx = ((bid >> 3) << 1) | (xcd & 1);  // 0..1439
    const int chunk = idx >> 4;                     // 0..89
    const int p  = (idx & 15) * 256 + threadIdx.x;
    const int v0 = chunk * VCHUNK;

    const float*  sg  = sinogram + (size_t)b * V * D;
    const float2* sg2b = sg2 + (size_t)b * V * D;
    const __half* sb  = sino + (size_t)b * V * D * RECH;

    // ---- phase A: coalesced streaming loads --------------------------------
    float gx[4], gy[4], sv[4];
    #pragma unroll
    for (int u = 0; u < 4; ++u) {
        const size_t gi = (size_t)(b * V + v0 + u) * P2 + p;
        const double gd = __builtin_nontemporal_load((const double*)grid + gi);
        const unsigned long long gu = __double_as_longlong(gd);
        gx[u] = __uint_as_float((unsigned)gu);
        gy[u] = __uint_as_float((unsigned)(gu >> 32));
        sv[u] = __builtin_nontemporal_load(sq + gi);
    }

    // ---- phase B: record gathers (2 per point) -----------------------------
    uint4    ra[4][2];
    unsigned rzu[4][2];
    float    rel[4][2];
    #pragma unroll
    for (int u = 0; u < 4; ++u) {
        const float fy = ((gy[u] + 1e-6f + 1.f) * (float)V - 1.f) * 0.5f;
        const int   yi = (int)fminf(fmaxf(rintf(fy), 0.f), (float)(V - 1));
        const float fx0 = ((gx[u] + 1e-6f + 1.f) * (float)D - 1.f) * 0.5f;
        #pragma unroll
        for (int sft = 0; sft < 2; ++sft) {
            const float fx = (sft == 0) ? (fx0 - 0.5f) : (fx0 + 0.5f);
            const int   xi = (int)fminf(fmaxf(rintf(fx), 0.f), (float)(D - 1));
            const float qc = ((float)xi + 0.5f) * (2.f / (float)D) - 1.f;
            rel[u][sft] = (gx[u] - qc) * (float)D;
            const __half* rec = sb + (size_t)(yi * D + xi) * RECH;
            ra[u][sft]  = *(const uint4*)rec;
            rzu[u][sft] = *(const unsigned*)(rec + 8);
        }
    }

    // ---- phase C: bilinear gathers -----------------------------------------
    float bl00[4], bl01[4], bl10[4], bl11[4], wxv[4], wyv[4];
    #pragma unroll
    for (int u = 0; u < 4; ++u) {
        float fxb = fminf(fmaxf(((gx[u] + 1.f) * (float)D - 1.f) * 0.5f, 0.f), (float)(D - 1));
        float fyb = fminf(fmaxf(((gy[u] + 1.f) * (float)V - 1.f) * 0.5f, 0.f), (float)(V - 1));
        const float x0 = floorf(fxb), y0 = floorf(fyb);
        wxv[u] = fxb - x0; wyv[u] = fyb - y0;
        const int x0i = (int)x0, y0i = (int)y0;
        const int y1i = min(y0i + 1, V - 1);
        if (PAIRED) {
            const float2 t = sg2b[y0i * D + x0i];
            const float2 u2 = sg2b[y1i * D + x0i];
            bl00[u] = t.x;  bl01[u] = t.y;
            bl10[u] = u2.x; bl11[u] = u2.y;
        } else {
            const int x1i = min(x0i + 1, D - 1);
            bl00[u] = sg[y0i * D + x0i]; bl01[u] = sg[y0i * D + x1i];
            bl10[u] = sg[y1i * D + x0i]; bl11[u] = sg[y1i * D + x1i];
        }
    }

    // ---- phase D: math ------------------------------------------------------
    float acc = 0.f;
    #pragma unroll
    for (int u = 0; u < 4; ++u) {
        float val[2], len[2];
        #pragma unroll
        for (int sft = 0; sft < 2; ++sft) {
            float q[9];
            {
                const uint4 a = ra[u][sft];
                union { unsigned uu; __half2 h; } c;
                float2 f;
                c.uu = a.x; f = __half22float2(c.h); q[0] = f.x; q[1] = f.y;
                c.uu = a.y; f = __half22float2(c.h); q[2] = f.x; q[3] = f.y;
                c.uu = a.z; f = __half22float2(c.h); q[4] = f.x; q[5] = f.y;
                c.uu = a.w; f = __half22float2(c.h); q[6] = f.x; q[7] = f.y;
                union { unsigned short us; __half hh; } c2;
                c2.us = (unsigned short)rzu[u][sft];
                q[8] = __half2float(c2.hh);
            }
            const float r = rel[u][sft];
            const float ang = r * 1.5707963267948966f;  // OMEGA
            float s1, c1;
            __sincosf(ang, &s1, &c1);
            const float c2 = fmaf(2.f * c1, c1, -1.f);
            const float s2 = 2.f * c1 * s1;
            const float c3 = fmaf(2.f * c1, c2, -c1);
            const float s3 = fmaf(2.f * c1, s2, -s1);
            const float c4 = fmaf(2.f * c1, c3, -c2);
            const float s4 = fmaf(2.f * c1, s3, -s2);

            float vv = q[0];
            vv = fmaf(q[1], c1, vv); vv = fmaf(q[2], c2, vv);
            vv = fmaf(q[3], c3, vv); vv = fmaf(q[4], c4, vv);
            vv = fmaf(q[5], s1, vv); vv = fmaf(q[6], s2, vv);
            vv = fmaf(q[7], s3, vv); vv = fmaf(q[8], s4, vv);
            val[sft] = vv;
            len[sft] = fabsf(r) + 1e-4f;
        }
        const float tot   = len[0] + len[1];
        const float recon = (val[0] * len[1] + val[1] * len[0]) / tot;

        const float wx = wxv[u], wy = wyv[u];
        const float bp = bl00[u] * (1.f - wx) * (1.f - wy) + bl01[u] * wx * (1.f - wy)
                       + bl10[u] * (1.f - wx) * wy         + bl11[u] * wx * wy;

        acc += (recon + bp) * sv[u] * 1e4f;
    }
    __builtin_nontemporal_store(acc, partial + ((size_t)chunk * B + b) * P2 + p);
}

// ---------------------------------------------------------------------------
// Kernel 3: fold the NCHUNK partials
// ---------------------------------------------------------------------------
__global__ __launch_bounds__(256) void reduce_kernel(
    const float* __restrict__ partial, float* __restrict__ out)
{
    const int i = blockIdx.x * 256 + threadIdx.x;   // 0..B*P2-1
    float a = 0.f;
    #pragma unroll 6
    for (int c = 0; c < NCHUNK; ++c)
        a += __builtin_nontemporal_load(partial + (size_t)c * B * P2 + i);
    out[i] = a;
}

// ---------------------------------------------------------------------------
extern "C" void kernel_launch(void* const* d_in, const int* in_sizes, int n_in,
                              void* d_out, int out_size, void* d_ws, size_t ws_size,
                              hipStream_t stream)
{
    const float* sinogram = (const float*)d_in[0];
    const float* feat     = (const float*)d_in[1];
    const float* grid     = (const float*)d_in[2];
    const float* sq       = (const float*)d_in[3];
    const float* w        = (const float*)d_in[4];
    const float* bias     = (const float*)d_in[5];
    float* out = (float*)d_out;

    const size_t sino_b = (size_t)B * V * D * RECH * sizeof(__half);   // 23.6 MB
    const size_t part_b = (size_t)NCHUNK * B * P2 * sizeof(float);     //  5.9 MB
    const size_t sg2_b  = (size_t)B * V * D * sizeof(float2);          //  5.9 MB

    __half* sino    = (__half*)d_ws;
    float*  partial = (float*)((char*)d_ws + sino_b);
    float2* sg2     = (float2*)((char*)d_ws + sino_b + part_b);
    const bool paired = (ws_size >= sino_b + part_b + sg2_b);

    conv_kernel<<<dim3(720), 256, 0, stream>>>(feat, w, bias, sino);
    if (paired) {
        build_sg2<<<dim3(2880), 256, 0, stream>>>(sinogram, sg2);
        sample_kernel<1><<<dim3(5760), 256, 0, stream>>>(sino, sinogram, sg2, grid, sq, partial);
    } else {
        sample_kernel<0><<<dim3(5760), 256, 0, stream>>>(sino, sinogram, sg2, grid, sq, partial);
    }
    reduce_kernel<<<dim3((B * P2) / 256), 256, 0, stream>>>(partial, out);
}